// Round 9
// baseline (374.875 us; speedup 1.0000x reference)
//
#include <hip/hip_runtime.h>
#include <hip/hip_bf16.h>

#define N_NODES 50000
#define N_EDGES 800000
#define N_GRAPHS 512
#define EMB 64
#define HID 128

// bf16 helpers: RNE pack, shift-unpack (bf16->f32 is exact)
__device__ __forceinline__ unsigned f2bf(float f) {
    unsigned x = __float_as_uint(f);
    return (x + 0x7fffu + ((x >> 16) & 1u)) >> 16;
}
__device__ __forceinline__ unsigned packbf(float lo, float hi) {
    return f2bf(lo) | (f2bf(hi) << 16);
}
__device__ __forceinline__ float bf_lo(unsigned u) { return __uint_as_float(u << 16); }
__device__ __forceinline__ float bf_hi(unsigned u) { return __uint_as_float(u & 0xffff0000u); }

// ------------------- embed gather + degree histogram + bf16 mirror of h0
__global__ void k_embed_hist(const int* __restrict__ x, const float* __restrict__ emb,
                             const int* __restrict__ ei, float* __restrict__ h0,
                             uint2* __restrict__ h0b, int* __restrict__ deg) {
    int t = blockIdx.x * 256 + threadIdx.x;
    if (t >= N_EDGES) return;
    int n = t >> 4, c4 = t & 15;
    const float4* e4 = (const float4*)emb;
    float4 v = e4[(size_t)x[n] * 16 + c4];
    ((float4*)h0)[(size_t)n * 16 + c4] = v;
    uint2 b; b.x = packbf(v.x, v.y); b.y = packbf(v.z, v.w);
    h0b[(size_t)n * 16 + c4] = b;
    atomicAdd(&deg[ei[N_EDGES + t]], 1);
}

// ---------------------------------------------------------------- 3-phase scan
__global__ void k_scanA(const int* __restrict__ deg, int* __restrict__ rowptr,
                        int* __restrict__ bsums) {
    __shared__ int s[256];
    int t = threadIdx.x, i = blockIdx.x * 256 + t;
    int v = (i < N_NODES) ? deg[i] : 0;
    s[t] = v; __syncthreads();
    int xv = v;
    for (int off = 1; off < 256; off <<= 1) {
        int y = (t >= off) ? s[t - off] : 0;
        __syncthreads();
        xv += y; s[t] = xv;
        __syncthreads();
    }
    if (i < N_NODES) rowptr[i] = xv - v;
    if (t == 255) bsums[blockIdx.x] = xv;
}

__global__ void k_scanB(int* __restrict__ bsums, int nb) {
    __shared__ int s[256];
    int t = threadIdx.x;
    int v = (t < nb) ? bsums[t] : 0;
    s[t] = v; __syncthreads();
    int xv = v;
    for (int off = 1; off < 256; off <<= 1) {
        int y = (t >= off) ? s[t - off] : 0;
        __syncthreads();
        xv += y; s[t] = xv;
        __syncthreads();
    }
    if (t < nb) bsums[t] = xv - v;
}

__global__ void k_scanC(int* __restrict__ rowptr, int* __restrict__ wp,
                        const int* __restrict__ bsums) {
    int i = blockIdx.x * 256 + threadIdx.x;
    if (i < N_NODES) {
        int v = rowptr[i] + bsums[blockIdx.x];
        rowptr[i] = v;
        wp[i] = v;
    }
    if (i == 0) rowptr[N_NODES] = N_EDGES;
}

// ---------------------------------------------------------------- edge scatter
__global__ void k_scatter(const int* __restrict__ ei, int* __restrict__ wp,
                          int* __restrict__ nbr) {
    int e = blockIdx.x * 256 + threadIdx.x;
    if (e >= N_EDGES) return;
    int s = ei[e], d = ei[N_EDGES + e];
    int pos = atomicAdd(&wp[d], 1);
    nbr[pos] = s;
}

// ------------------------------------------ sliced bf16 agg device function
// One block gathers ONE 32-feat column slice (8 uint2 = 64B/row) for 64 nodes.
// 8 waves x 8 nodes/wave x 8 lanes/node. Slice is XCD-stable (slice = bid mod
// SLICES with SLICES | 8), so each XCD's L2 only caches its 3.2 MB slice.
// Accumulate f32, write f32 mean slice. 8-deep ILP.
template <int F>
__device__ __forceinline__ void agg_slice(const uint2* __restrict__ hb,
                                          const int* __restrict__ rowptr,
                                          const int* __restrict__ nbr,
                                          float* __restrict__ mean,
                                          int chunk, int slice, int t) {
    constexpr int CU2 = F / 4;          // uint2 (and float4) per full row
    int wl = t >> 6, l = t & 63;
    int n = chunk * 64 + wl * 8 + (l >> 3);
    int cu = slice * 8 + (l & 7);
    if (n >= N_NODES) return;
    float4* m4 = (float4*)mean;

    int r0 = rowptr[n], r1 = rowptr[n + 1];
    float inv = 1.0f / (float)max(r1 - r0, 1);

    float4 a[8];
    #pragma unroll
    for (int u = 0; u < 8; ++u) a[u] = make_float4(0.f, 0.f, 0.f, 0.f);

    int i = r0;
    for (; i + 7 < r1; i += 8) {
        int s0 = nbr[i + 0], s1 = nbr[i + 1], s2 = nbr[i + 2], s3 = nbr[i + 3];
        int s4 = nbr[i + 4], s5 = nbr[i + 5], s6 = nbr[i + 6], s7 = nbr[i + 7];
        uint2 v0 = hb[(size_t)s0 * CU2 + cu];
        uint2 v1 = hb[(size_t)s1 * CU2 + cu];
        uint2 v2 = hb[(size_t)s2 * CU2 + cu];
        uint2 v3 = hb[(size_t)s3 * CU2 + cu];
        uint2 v4 = hb[(size_t)s4 * CU2 + cu];
        uint2 v5 = hb[(size_t)s5 * CU2 + cu];
        uint2 v6 = hb[(size_t)s6 * CU2 + cu];
        uint2 v7 = hb[(size_t)s7 * CU2 + cu];
        a[0].x += bf_lo(v0.x); a[0].y += bf_hi(v0.x); a[0].z += bf_lo(v0.y); a[0].w += bf_hi(v0.y);
        a[1].x += bf_lo(v1.x); a[1].y += bf_hi(v1.x); a[1].z += bf_lo(v1.y); a[1].w += bf_hi(v1.y);
        a[2].x += bf_lo(v2.x); a[2].y += bf_hi(v2.x); a[2].z += bf_lo(v2.y); a[2].w += bf_hi(v2.y);
        a[3].x += bf_lo(v3.x); a[3].y += bf_hi(v3.x); a[3].z += bf_lo(v3.y); a[3].w += bf_hi(v3.y);
        a[4].x += bf_lo(v4.x); a[4].y += bf_hi(v4.x); a[4].z += bf_lo(v4.y); a[4].w += bf_hi(v4.y);
        a[5].x += bf_lo(v5.x); a[5].y += bf_hi(v5.x); a[5].z += bf_lo(v5.y); a[5].w += bf_hi(v5.y);
        a[6].x += bf_lo(v6.x); a[6].y += bf_hi(v6.x); a[6].z += bf_lo(v6.y); a[6].w += bf_hi(v6.y);
        a[7].x += bf_lo(v7.x); a[7].y += bf_hi(v7.x); a[7].z += bf_lo(v7.y); a[7].w += bf_hi(v7.y);
    }
    for (; i + 3 < r1; i += 4) {
        int s0 = nbr[i + 0], s1 = nbr[i + 1], s2 = nbr[i + 2], s3 = nbr[i + 3];
        uint2 v0 = hb[(size_t)s0 * CU2 + cu];
        uint2 v1 = hb[(size_t)s1 * CU2 + cu];
        uint2 v2 = hb[(size_t)s2 * CU2 + cu];
        uint2 v3 = hb[(size_t)s3 * CU2 + cu];
        a[0].x += bf_lo(v0.x); a[0].y += bf_hi(v0.x); a[0].z += bf_lo(v0.y); a[0].w += bf_hi(v0.y);
        a[1].x += bf_lo(v1.x); a[1].y += bf_hi(v1.x); a[1].z += bf_lo(v1.y); a[1].w += bf_hi(v1.y);
        a[2].x += bf_lo(v2.x); a[2].y += bf_hi(v2.x); a[2].z += bf_lo(v2.y); a[2].w += bf_hi(v2.y);
        a[3].x += bf_lo(v3.x); a[3].y += bf_hi(v3.x); a[3].z += bf_lo(v3.y); a[3].w += bf_hi(v3.y);
    }
    for (; i < r1; ++i) {
        uint2 v = hb[(size_t)nbr[i] * CU2 + cu];
        a[0].x += bf_lo(v.x); a[0].y += bf_hi(v.x); a[0].z += bf_lo(v.y); a[0].w += bf_hi(v.y);
    }
    #pragma unroll
    for (int u = 1; u < 8; ++u) {
        a[0].x += a[u].x; a[0].y += a[u].y; a[0].z += a[u].z; a[0].w += a[u].w;
    }
    m4[(size_t)n * CU2 + cu] = make_float4(a[0].x * inv, a[0].y * inv,
                                           a[0].z * inv, a[0].w * inv);
}

// ------------------------------------------------------- GEMM device function
// 64-node tile staged in LDS (stride K+2); 8 waves; wave w -> cols [16w,16w+16);
// lane -> node; weights via uniform s_load streams.
// MEAN=false: acc=bias, write raw. MEAN=true: acc=out[] RMW, relu.
// WB=true: also write bf16 mirror of the (relu'd) output.
template <int K, bool MEAN, bool WB>
__device__ __forceinline__ void gemm_tile(const float* __restrict__ hin,
                                          const float* __restrict__ w,
                                          const float* __restrict__ bias,
                                          float* __restrict__ out,
                                          uint2* __restrict__ outb,
                                          int blk, int t, float* ls) {
    constexpr int LS = K + 2;
    constexpr int C4 = K / 4;
    int base = blk * 64;
    int lane = t & 63;
    int wid = __builtin_amdgcn_readfirstlane(t >> 6);
    int j0 = wid * 16;
    int node = base + lane;
    bool valid = node < N_NODES;

    const float4* h4 = (const float4*)hin;
    for (int idx = t; idx < 64 * C4; idx += 512) {
        int r = idx / C4, c4 = idx % C4;
        float4 v = (base + r < N_NODES) ? h4[(size_t)(base + r) * C4 + c4]
                                        : make_float4(0.f, 0.f, 0.f, 0.f);
        float* dp = &ls[r * LS + c4 * 4];
        dp[0] = v.x; dp[1] = v.y; dp[2] = v.z; dp[3] = v.w;
    }
    __syncthreads();

    float acc[16];
    if constexpr (MEAN) {
        const float4* o4 = (const float4*)out;
        #pragma unroll
        for (int jj = 0; jj < 4; ++jj) {
            float4 v = valid ? o4[(size_t)node * 32 + wid * 4 + jj]
                             : make_float4(0.f, 0.f, 0.f, 0.f);
            acc[jj * 4 + 0] = v.x; acc[jj * 4 + 1] = v.y;
            acc[jj * 4 + 2] = v.z; acc[jj * 4 + 3] = v.w;
        }
    } else {
        #pragma unroll
        for (int j = 0; j < 16; ++j) acc[j] = bias[j0 + j];
    }

    const float* lrow = &ls[lane * LS];
    #pragma unroll 4
    for (int k = 0; k < K; ++k) {
        float hv = lrow[k];
        const float* wk = &w[(size_t)k * 128 + j0];
        #pragma unroll
        for (int j = 0; j < 16; ++j) acc[j] = fmaf(hv, wk[j], acc[j]);
    }

    if (!valid) return;
    float4* o4 = (float4*)out;
    #pragma unroll
    for (int jj = 0; jj < 4; ++jj) {
        float4 v;
        if constexpr (MEAN) {
            v.x = fmaxf(acc[jj * 4 + 0], 0.f);
            v.y = fmaxf(acc[jj * 4 + 1], 0.f);
            v.z = fmaxf(acc[jj * 4 + 2], 0.f);
            v.w = fmaxf(acc[jj * 4 + 3], 0.f);
        } else {
            v.x = acc[jj * 4 + 0]; v.y = acc[jj * 4 + 1];
            v.z = acc[jj * 4 + 2]; v.w = acc[jj * 4 + 3];
        }
        o4[(size_t)node * 32 + wid * 4 + jj] = v;
        if constexpr (WB) {
            uint2 u; u.x = packbf(v.x, v.y); u.y = packbf(v.z, v.w);
            outb[(size_t)node * 32 + wid * 4 + jj] = u;
        }
    }
}

// ------------------------------------------------- fused agg ∥ selfGEMM layers
// Group layout ties slice to bid%SLICES (XCD-stable: SLICES | 8 | group size).
// fuse1: groups of 24 = 16 agg (8 chunks x 2 slices) + 8 GEMM.
__global__ __launch_bounds__(512) void k_fuse1(
    const float* __restrict__ h0, const uint2* __restrict__ h0b,
    const int* __restrict__ rowptr, const int* __restrict__ nbr,
    float* __restrict__ mean1, const float* __restrict__ w1r,
    const float* __restrict__ b1, float* __restrict__ h1) {
    __shared__ float ls[64 * (64 + 2)];
    int b = blockIdx.x, g = b / 24, r = b % 24;
    if (r < 16)
        agg_slice<64>(h0b, rowptr, nbr, mean1, g * 8 + (r >> 1), r & 1, threadIdx.x);
    else
        gemm_tile<64, false, false>(h0, w1r, b1, h1, nullptr, g * 8 + (r - 16), threadIdx.x, ls);
}

// fuse2: groups of 40 = 32 agg (8 chunks x 4 slices) + 8 GEMM.
__global__ __launch_bounds__(512) void k_fuse2(
    const float* __restrict__ h1, const uint2* __restrict__ h1b,
    const int* __restrict__ rowptr, const int* __restrict__ nbr,
    float* __restrict__ mean2, const float* __restrict__ w2r,
    const float* __restrict__ b2, float* __restrict__ h2) {
    __shared__ float ls[64 * (128 + 2)];
    int b = blockIdx.x, g = b / 40, r = b % 40;
    if (r < 32)
        agg_slice<128>(h1b, rowptr, nbr, mean2, g * 8 + (r >> 2), r & 3, threadIdx.x);
    else
        gemm_tile<128, false, false>(h1, w2r, b2, h2, nullptr, g * 8 + (r - 32), threadIdx.x, ls);
}

// ------------------------------------------------- mean GEMMs (in-place RMW)
__global__ __launch_bounds__(512) void k_gemm_mean64(
    const float* __restrict__ mean1, const float* __restrict__ w1l,
    float* __restrict__ h1, uint2* __restrict__ h1b) {
    __shared__ float ls[64 * (64 + 2)];
    gemm_tile<64, true, true>(mean1, w1l, nullptr, h1, h1b, blockIdx.x, threadIdx.x, ls);
}

__global__ __launch_bounds__(512) void k_gemm_mean128(
    const float* __restrict__ mean2, const float* __restrict__ w2l,
    float* __restrict__ h2) {
    __shared__ float ls[64 * (128 + 2)];
    gemm_tile<128, true, false>(mean2, w2l, nullptr, h2, nullptr, blockIdx.x, threadIdx.x, ls);
}

// ---------------------------------------------------------------- pool + head
__global__ void k_pool_head(const float* __restrict__ h2, const int* __restrict__ batch,
                            const float* __restrict__ w_out, const float* __restrict__ b_out,
                            float* __restrict__ out) {
    int g = blockIdx.x;
    int lo = 0, hi = N_NODES;
    while (lo < hi) { int mid = (lo + hi) >> 1; if (batch[mid] < g) lo = mid + 1; else hi = mid; }
    int s = lo;
    lo = s; hi = N_NODES;
    while (lo < hi) { int mid = (lo + hi) >> 1; if (batch[mid] < g + 1) lo = mid + 1; else hi = mid; }
    int e = lo;

    int f = threadIdx.x & 127, half = threadIdx.x >> 7;
    float acc = 0.0f;
    for (int r = s + half; r < e; r += 2) acc += h2[(size_t)r * 128 + f];
    __shared__ float tmp[256];
    tmp[threadIdx.x] = acc;
    __syncthreads();
    if (half == 0) {
        float p = (tmp[f] + tmp[f + 128]) / (float)max(e - s, 1);
        tmp[f]       = p * w_out[f * 2 + 0];
        tmp[f + 128] = p * w_out[f * 2 + 1];
    }
    __syncthreads();
    for (int str = 64; str > 0; str >>= 1) {
        if (threadIdx.x < str) {
            tmp[threadIdx.x] += tmp[threadIdx.x + str];
            tmp[threadIdx.x + 128] += tmp[threadIdx.x + 128 + str];
        }
        __syncthreads();
    }
    if (threadIdx.x == 0) {
        out[(size_t)g * 2 + 0] = tmp[0] + b_out[0];
        out[(size_t)g * 2 + 1] = tmp[128] + b_out[1];
    }
}

// ---------------------------------------------------------------- launch
extern "C" void kernel_launch(void* const* d_in, const int* in_sizes, int n_in,
                              void* d_out, int out_size, void* d_ws, size_t ws_size,
                              hipStream_t stream) {
    const int*   x      = (const int*)d_in[0];
    const int*   ei     = (const int*)d_in[1];
    const int*   batch  = (const int*)d_in[2];
    const float* emb    = (const float*)d_in[3];
    const float* w1_l   = (const float*)d_in[4];
    const float* b1     = (const float*)d_in[5];
    const float* w1_r   = (const float*)d_in[6];
    const float* w2_l   = (const float*)d_in[7];
    const float* b2     = (const float*)d_in[8];
    const float* w2_r   = (const float*)d_in[9];
    const float* w_out  = (const float*)d_in[10];
    const float* b_out  = (const float*)d_in[11];
    float* out = (float*)d_out;

    // workspace regions (f32 units) — recycled across phases:
    //  A: h0 (N*64)     -> h1b (N*128 bf16) after h0 dead
    //  B: mean1 (N*64)
    //  C: h1 (N*128)    -> h2 in-place (per-block stage-then-write, disjoint)
    //  D: mean2 (N*128) ; first half doubles as h0b until fuse1 done
    float* F = (float*)d_ws;
    float* A = F;
    float* B = A + (size_t)N_NODES * 64;
    float* C = B + (size_t)N_NODES * 64;
    float* D = C + (size_t)N_NODES * 128;
    float* h0    = A;
    uint2* h1b   = (uint2*)A;
    float* mean1 = B;
    float* h1    = C;
    float* h2    = C;
    float* mean2 = D;
    uint2* h0b   = (uint2*)D;
    int*   deg   = (int*)(D + (size_t)N_NODES * 128);
    int*   rowptr= deg + N_NODES;                     // N+1
    int*   wp    = rowptr + N_NODES + 1;              // N
    int*   nbr   = wp + N_NODES;                      // E
    int*   bsums = nbr + N_EDGES;                     // 256

    const int NB = (N_NODES + 255) / 256;             // 196
    const int NG = (N_NODES + 511) / 512;             // 98 groups of 8 chunks

    hipMemsetAsync(deg, 0, (size_t)N_NODES * sizeof(int), stream);

    k_embed_hist<<<(N_EDGES + 255) / 256, 256, 0, stream>>>(x, emb, ei, h0, h0b, deg);
    k_scanA<<<NB, 256, 0, stream>>>(deg, rowptr, bsums);
    k_scanB<<<1, 256, 0, stream>>>(bsums, NB);
    k_scanC<<<NB, 256, 0, stream>>>(rowptr, wp, bsums);
    k_scatter<<<(N_EDGES + 255) / 256, 256, 0, stream>>>(ei, wp, nbr);

    // layer 1: sliced agg64 (2 slices) ∥ selfGEMM1, groups of 24
    k_fuse1<<<NG * 24, 512, 0, stream>>>(h0, h0b, rowptr, nbr, mean1, w1_r, b1, h1);
    k_gemm_mean64<<<(N_NODES + 63) / 64, 512, 0, stream>>>(mean1, w1_l, h1, h1b);

    // layer 2: sliced agg128 (4 slices) ∥ selfGEMM2, groups of 40; h2 overwrites h1
    k_fuse2<<<NG * 40, 512, 0, stream>>>(h1, h1b, rowptr, nbr, mean2, w2_r, b2, h2);
    k_gemm_mean128<<<(N_NODES + 63) / 64, 512, 0, stream>>>(mean2, w2_l, h2);

    // pool + head
    k_pool_head<<<N_GRAPHS, 256, 0, stream>>>(h2, batch, w_out, b_out, out);

    (void)in_sizes; (void)n_in; (void)out_size; (void)ws_size;
}

// Round 10
// 332.784 us; speedup vs baseline: 1.1265x; 1.1265x over previous
//
#include <hip/hip_runtime.h>
#include <hip/hip_bf16.h>

#define N_NODES 50000
#define N_EDGES 800000
#define N_GRAPHS 512
#define EMB 64
#define HID 128

// bf16 helpers: RNE pack, shift-unpack (bf16->f32 is exact)
__device__ __forceinline__ unsigned f2bf(float f) {
    unsigned x = __float_as_uint(f);
    return (x + 0x7fffu + ((x >> 16) & 1u)) >> 16;
}
__device__ __forceinline__ unsigned packbf(float lo, float hi) {
    return f2bf(lo) | (f2bf(hi) << 16);
}
__device__ __forceinline__ float bf_lo(unsigned u) { return __uint_as_float(u << 16); }
__device__ __forceinline__ float bf_hi(unsigned u) { return __uint_as_float(u & 0xffff0000u); }

// ------------------- embed gather (bf16 only) + degree histogram
__global__ void k_embed_hist(const int* __restrict__ x, const float* __restrict__ emb,
                             const int* __restrict__ ei, uint2* __restrict__ h0b,
                             int* __restrict__ deg) {
    int t = blockIdx.x * 256 + threadIdx.x;
    if (t >= N_EDGES) return;
    int n = t >> 4, c4 = t & 15;
    const float4* e4 = (const float4*)emb;
    float4 v = e4[(size_t)x[n] * 16 + c4];
    uint2 b; b.x = packbf(v.x, v.y); b.y = packbf(v.z, v.w);
    h0b[(size_t)n * 16 + c4] = b;
    atomicAdd(&deg[ei[N_EDGES + t]], 1);
}

// ---------------------------------------------------------------- 3-phase scan
__global__ void k_scanA(const int* __restrict__ deg, int* __restrict__ rowptr,
                        int* __restrict__ bsums) {
    __shared__ int s[256];
    int t = threadIdx.x, i = blockIdx.x * 256 + t;
    int v = (i < N_NODES) ? deg[i] : 0;
    s[t] = v; __syncthreads();
    int xv = v;
    for (int off = 1; off < 256; off <<= 1) {
        int y = (t >= off) ? s[t - off] : 0;
        __syncthreads();
        xv += y; s[t] = xv;
        __syncthreads();
    }
    if (i < N_NODES) rowptr[i] = xv - v;
    if (t == 255) bsums[blockIdx.x] = xv;
}

__global__ void k_scanB(int* __restrict__ bsums, int nb) {
    __shared__ int s[256];
    int t = threadIdx.x;
    int v = (t < nb) ? bsums[t] : 0;
    s[t] = v; __syncthreads();
    int xv = v;
    for (int off = 1; off < 256; off <<= 1) {
        int y = (t >= off) ? s[t - off] : 0;
        __syncthreads();
        xv += y; s[t] = xv;
        __syncthreads();
    }
    if (t < nb) bsums[t] = xv - v;
}

__global__ void k_scanC(int* __restrict__ rowptr, int* __restrict__ wp,
                        const int* __restrict__ bsums) {
    int i = blockIdx.x * 256 + threadIdx.x;
    if (i < N_NODES) {
        int v = rowptr[i] + bsums[blockIdx.x];
        rowptr[i] = v;
        wp[i] = v;
    }
    if (i == 0) rowptr[N_NODES] = N_EDGES;
}

// ---------------------------------------------------------------- edge scatter
__global__ void k_scatter(const int* __restrict__ ei, int* __restrict__ wp,
                          int* __restrict__ nbr) {
    int e = blockIdx.x * 256 + threadIdx.x;
    if (e >= N_EDGES) return;
    int s = ei[e], d = ei[N_EDGES + e];
    int pos = atomicAdd(&wp[d], 1);
    nbr[pos] = s;
}

// ----------------------------------------------- bf16 agg (R8 structure)
// F=128: 2 nodes/wave (32 lanes x uint2); F=64: 4 nodes/wave. f32 accum, 8-deep ILP.
template <int F>
__device__ __forceinline__ void agg_tile_bf(const uint2* __restrict__ hb,
                                            const int* __restrict__ rowptr,
                                            const int* __restrict__ nbr,
                                            float* __restrict__ mean,
                                            int aggIdx, int t) {
    int wl = t >> 6;
    int l = t & 63;
    float4* m4 = (float4*)mean;

    int n, c;
    if constexpr (F == 128) { n = aggIdx * 16 + wl * 2 + (l >> 5); c = l & 31; }
    else                    { n = aggIdx * 32 + wl * 4 + (l >> 4); c = l & 15; }
    if (n >= N_NODES) return;
    constexpr int CU2 = F / 4;        // uint2 per row

    int r0 = rowptr[n], r1 = rowptr[n + 1];
    float inv = 1.0f / (float)max(r1 - r0, 1);

    float4 a[8];
    #pragma unroll
    for (int u = 0; u < 8; ++u) a[u] = make_float4(0.f, 0.f, 0.f, 0.f);

    int i = r0;
    for (; i + 7 < r1; i += 8) {
        int s0 = nbr[i + 0], s1 = nbr[i + 1], s2 = nbr[i + 2], s3 = nbr[i + 3];
        int s4 = nbr[i + 4], s5 = nbr[i + 5], s6 = nbr[i + 6], s7 = nbr[i + 7];
        uint2 v0 = hb[(size_t)s0 * CU2 + c];
        uint2 v1 = hb[(size_t)s1 * CU2 + c];
        uint2 v2 = hb[(size_t)s2 * CU2 + c];
        uint2 v3 = hb[(size_t)s3 * CU2 + c];
        uint2 v4 = hb[(size_t)s4 * CU2 + c];
        uint2 v5 = hb[(size_t)s5 * CU2 + c];
        uint2 v6 = hb[(size_t)s6 * CU2 + c];
        uint2 v7 = hb[(size_t)s7 * CU2 + c];
        a[0].x += bf_lo(v0.x); a[0].y += bf_hi(v0.x); a[0].z += bf_lo(v0.y); a[0].w += bf_hi(v0.y);
        a[1].x += bf_lo(v1.x); a[1].y += bf_hi(v1.x); a[1].z += bf_lo(v1.y); a[1].w += bf_hi(v1.y);
        a[2].x += bf_lo(v2.x); a[2].y += bf_hi(v2.x); a[2].z += bf_lo(v2.y); a[2].w += bf_hi(v2.y);
        a[3].x += bf_lo(v3.x); a[3].y += bf_hi(v3.x); a[3].z += bf_lo(v3.y); a[3].w += bf_hi(v3.y);
        a[4].x += bf_lo(v4.x); a[4].y += bf_hi(v4.x); a[4].z += bf_lo(v4.y); a[4].w += bf_hi(v4.y);
        a[5].x += bf_lo(v5.x); a[5].y += bf_hi(v5.x); a[5].z += bf_lo(v5.y); a[5].w += bf_hi(v5.y);
        a[6].x += bf_lo(v6.x); a[6].y += bf_hi(v6.x); a[6].z += bf_lo(v6.y); a[6].w += bf_hi(v6.y);
        a[7].x += bf_lo(v7.x); a[7].y += bf_hi(v7.x); a[7].z += bf_lo(v7.y); a[7].w += bf_hi(v7.y);
    }
    for (; i + 3 < r1; i += 4) {
        int s0 = nbr[i + 0], s1 = nbr[i + 1], s2 = nbr[i + 2], s3 = nbr[i + 3];
        uint2 v0 = hb[(size_t)s0 * CU2 + c];
        uint2 v1 = hb[(size_t)s1 * CU2 + c];
        uint2 v2 = hb[(size_t)s2 * CU2 + c];
        uint2 v3 = hb[(size_t)s3 * CU2 + c];
        a[0].x += bf_lo(v0.x); a[0].y += bf_hi(v0.x); a[0].z += bf_lo(v0.y); a[0].w += bf_hi(v0.y);
        a[1].x += bf_lo(v1.x); a[1].y += bf_hi(v1.x); a[1].z += bf_lo(v1.y); a[1].w += bf_hi(v1.y);
        a[2].x += bf_lo(v2.x); a[2].y += bf_hi(v2.x); a[2].z += bf_lo(v2.y); a[2].w += bf_hi(v2.y);
        a[3].x += bf_lo(v3.x); a[3].y += bf_hi(v3.x); a[3].z += bf_lo(v3.y); a[3].w += bf_hi(v3.y);
    }
    for (; i < r1; ++i) {
        uint2 v = hb[(size_t)nbr[i] * CU2 + c];
        a[0].x += bf_lo(v.x); a[0].y += bf_hi(v.x); a[0].z += bf_lo(v.y); a[0].w += bf_hi(v.y);
    }
    #pragma unroll
    for (int u = 1; u < 8; ++u) {
        a[0].x += a[u].x; a[0].y += a[u].y; a[0].z += a[u].z; a[0].w += a[u].w;
    }
    m4[(size_t)n * CU2 + c] = make_float4(a[0].x * inv, a[0].y * inv,
                                          a[0].z * inv, a[0].w * inv);
}

// --------------------------------------------------- LDS staging + GEMM core
template <int K>
__device__ __forceinline__ void stage_f32(const float* __restrict__ hin, int base,
                                          int t, float* ls) {
    constexpr int LS = K + 2, C4 = K / 4;
    const float4* h4 = (const float4*)hin;
    for (int idx = t; idx < 64 * C4; idx += 512) {
        int r = idx / C4, c = idx % C4;
        float4 v = (base + r < N_NODES) ? h4[(size_t)(base + r) * C4 + c]
                                        : make_float4(0.f, 0.f, 0.f, 0.f);
        float* dp = &ls[r * LS + c * 4];
        dp[0] = v.x; dp[1] = v.y; dp[2] = v.z; dp[3] = v.w;
    }
}

template <int K>
__device__ __forceinline__ void stage_bf(const uint2* __restrict__ hb, int base,
                                         int t, float* ls) {
    constexpr int LS = K + 2, C2 = K / 4;   // uint2 per row
    for (int idx = t; idx < 64 * C2; idx += 512) {
        int r = idx / C2, c = idx % C2;
        uint2 v = (base + r < N_NODES) ? hb[(size_t)(base + r) * C2 + c]
                                       : make_uint2(0u, 0u);
        float* dp = &ls[r * LS + c * 4];
        dp[0] = bf_lo(v.x); dp[1] = bf_hi(v.x);
        dp[2] = bf_lo(v.y); dp[3] = bf_hi(v.y);
    }
}

template <int K>
__device__ __forceinline__ void gemm_core(const float* __restrict__ lrow,
                                          const float* __restrict__ w,
                                          int j0, float (&acc)[16]) {
    #pragma unroll 4
    for (int k = 0; k < K; ++k) {
        float hv = lrow[k];
        const float* wk = &w[(size_t)k * 128 + j0];
        #pragma unroll
        for (int j = 0; j < 16; ++j) acc[j] = fmaf(hv, wk[j], acc[j]);
    }
}

// ------------------------------------------------- fused agg ∥ selfGEMM layers
__global__ __launch_bounds__(512) void k_fuse1(
    const uint2* __restrict__ h0b, const int* __restrict__ rowptr,
    const int* __restrict__ nbr, float* __restrict__ mean1,
    const float* __restrict__ w1r, const float* __restrict__ b1,
    float* __restrict__ pre1) {
    __shared__ float ls[64 * 66];
    int b = blockIdx.x, t = threadIdx.x;
    if (b % 3 == 2) {
        int base = (b / 3) * 64;
        stage_bf<64>(h0b, base, t, ls);
        __syncthreads();
        int lane = t & 63, wid = __builtin_amdgcn_readfirstlane(t >> 6), j0 = wid * 16;
        int node = base + lane;
        float acc[16];
        #pragma unroll
        for (int j = 0; j < 16; ++j) acc[j] = b1[j0 + j];
        gemm_core<64>(&ls[lane * 66], w1r, j0, acc);
        if (node < N_NODES) {
            float4* o4 = (float4*)pre1;
            #pragma unroll
            for (int jj = 0; jj < 4; ++jj)
                o4[(size_t)node * 32 + wid * 4 + jj] =
                    make_float4(acc[jj*4], acc[jj*4+1], acc[jj*4+2], acc[jj*4+3]);
        }
    } else {
        agg_tile_bf<64>(h0b, rowptr, nbr, mean1, (b / 3) * 2 + (b % 3), t);
    }
}

__global__ __launch_bounds__(512) void k_fuse2(
    const uint2* __restrict__ h1b, const int* __restrict__ rowptr,
    const int* __restrict__ nbr, float* __restrict__ mean2,
    const float* __restrict__ w2r, const float* __restrict__ b2,
    float* __restrict__ pre2) {
    __shared__ float ls[64 * 130];
    int b = blockIdx.x, t = threadIdx.x;
    if (b % 5 == 4) {
        int base = (b / 5) * 64;
        stage_bf<128>(h1b, base, t, ls);
        __syncthreads();
        int lane = t & 63, wid = __builtin_amdgcn_readfirstlane(t >> 6), j0 = wid * 16;
        int node = base + lane;
        float acc[16];
        #pragma unroll
        for (int j = 0; j < 16; ++j) acc[j] = b2[j0 + j];
        gemm_core<128>(&ls[lane * 130], w2r, j0, acc);
        if (node < N_NODES) {
            float4* o4 = (float4*)pre2;
            #pragma unroll
            for (int jj = 0; jj < 4; ++jj)
                o4[(size_t)node * 32 + wid * 4 + jj] =
                    make_float4(acc[jj*4], acc[jj*4+1], acc[jj*4+2], acc[jj*4+3]);
        }
    } else {
        agg_tile_bf<128>(h1b, rowptr, nbr, mean2, (b / 5) * 4 + (b % 5), t);
    }
}

// --------------------- meanGEMM layer1: RMW pre1, relu, write bf16 h1b only
// NOTE: h1b aliases mean1 (same bytes). Safe: tile staged to LDS before writes.
__global__ __launch_bounds__(512) void k_gemm_mean64(
    const float* __restrict__ mean1, const float* __restrict__ w1l,
    const float* __restrict__ pre1, uint2* __restrict__ h1b) {
    __shared__ float ls[64 * 66];
    int t = threadIdx.x, base = blockIdx.x * 64;
    stage_f32<64>(mean1, base, t, ls);
    __syncthreads();
    int lane = t & 63, wid = __builtin_amdgcn_readfirstlane(t >> 6), j0 = wid * 16;
    int node = base + lane;
    bool valid = node < N_NODES;
    float acc[16];
    const float4* p4 = (const float4*)pre1;
    #pragma unroll
    for (int jj = 0; jj < 4; ++jj) {
        float4 v = valid ? p4[(size_t)node * 32 + wid * 4 + jj]
                         : make_float4(0.f, 0.f, 0.f, 0.f);
        acc[jj*4] = v.x; acc[jj*4+1] = v.y; acc[jj*4+2] = v.z; acc[jj*4+3] = v.w;
    }
    gemm_core<64>(&ls[lane * 66], w1l, j0, acc);
    if (!valid) return;
    #pragma unroll
    for (int jj = 0; jj < 4; ++jj) {
        float a0 = fmaxf(acc[jj*4+0], 0.f), a1 = fmaxf(acc[jj*4+1], 0.f);
        float a2 = fmaxf(acc[jj*4+2], 0.f), a3 = fmaxf(acc[jj*4+3], 0.f);
        uint2 u; u.x = packbf(a0, a1); u.y = packbf(a2, a3);
        h1b[(size_t)node * 32 + wid * 4 + jj] = u;
    }
}

// ---- meanGEMM layer2 + fused pool: RMW pre2, relu, LDS segment-reduce, atomic
__global__ __launch_bounds__(512) void k_mean128_pool(
    const float* __restrict__ mean2, const float* __restrict__ w2l,
    const float* __restrict__ pre2, const int* __restrict__ batch,
    float* __restrict__ pooled) {
    __shared__ float ls[64 * 130];
    __shared__ int bb[64];
    int t = threadIdx.x, base = blockIdx.x * 64;
    stage_f32<128>(mean2, base, t, ls);
    if (t < 64) bb[t] = (base + t < N_NODES) ? batch[base + t] : -1;
    __syncthreads();
    int lane = t & 63, wid = __builtin_amdgcn_readfirstlane(t >> 6), j0 = wid * 16;
    int node = base + lane;
    bool valid = node < N_NODES;
    float acc[16];
    const float4* p4 = (const float4*)pre2;
    #pragma unroll
    for (int jj = 0; jj < 4; ++jj) {
        float4 v = valid ? p4[(size_t)node * 32 + wid * 4 + jj]
                         : make_float4(0.f, 0.f, 0.f, 0.f);
        acc[jj*4] = v.x; acc[jj*4+1] = v.y; acc[jj*4+2] = v.z; acc[jj*4+3] = v.w;
    }
    gemm_core<128>(&ls[lane * 130], w2l, j0, acc);
    __syncthreads();                              // done reading staged tile
    #pragma unroll
    for (int j = 0; j < 16; ++j)
        ls[lane * 129 + j0 + j] = valid ? fmaxf(acc[j], 0.f) : 0.f;
    __syncthreads();
    if (t < 128) {                                // segment-reduce 64 sorted rows
        int col = t;
        float run = 0.f;
        int gcur = bb[0];
        for (int r = 0; r < 64; ++r) {
            int g = bb[r];
            if (g != gcur) {
                if (gcur >= 0) atomicAdd(&pooled[gcur * 128 + col], run);
                run = 0.f; gcur = g;
            }
            run += ls[r * 129 + col];
        }
        if (gcur >= 0) atomicAdd(&pooled[gcur * 128 + col], run);
    }
}

// ---------------------------------------------------------------- head
__global__ void k_head(const float* __restrict__ pooled, const int* __restrict__ batch,
                       const float* __restrict__ w_out, const float* __restrict__ b_out,
                       float* __restrict__ out) {
    int g = blockIdx.x, f = threadIdx.x;          // 128 threads
    int lo = 0, hi = N_NODES;
    while (lo < hi) { int m = (lo + hi) >> 1; if (batch[m] < g) lo = m + 1; else hi = m; }
    int s = lo;
    lo = s; hi = N_NODES;
    while (lo < hi) { int m = (lo + hi) >> 1; if (batch[m] < g + 1) lo = m + 1; else hi = m; }
    int cnt = lo - s;
    float p = pooled[(size_t)g * 128 + f] / (float)max(cnt, 1);
    __shared__ float red[256];
    red[f] = p * w_out[f * 2 + 0];
    red[128 + f] = p * w_out[f * 2 + 1];
    __syncthreads();
    for (int st = 64; st > 0; st >>= 1) {
        if (f < st) { red[f] += red[f + st]; red[128 + f] += red[128 + f + st]; }
        __syncthreads();
    }
    if (f == 0) {
        out[(size_t)g * 2 + 0] = red[0] + b_out[0];
        out[(size_t)g * 2 + 1] = red[128] + b_out[1];
    }
}

// ---------------------------------------------------------------- launch
extern "C" void kernel_launch(void* const* d_in, const int* in_sizes, int n_in,
                              void* d_out, int out_size, void* d_ws, size_t ws_size,
                              hipStream_t stream) {
    const int*   x      = (const int*)d_in[0];
    const int*   ei     = (const int*)d_in[1];
    const int*   batch  = (const int*)d_in[2];
    const float* emb    = (const float*)d_in[3];
    const float* w1_l   = (const float*)d_in[4];
    const float* b1     = (const float*)d_in[5];
    const float* w1_r   = (const float*)d_in[6];
    const float* w2_l   = (const float*)d_in[7];
    const float* b2     = (const float*)d_in[8];
    const float* w2_r   = (const float*)d_in[9];
    const float* w_out  = (const float*)d_in[10];
    const float* b_out  = (const float*)d_in[11];
    float* out = (float*)d_out;

    // workspace (f32 units), recycled:
    //  R0: mean1 (N*64)  -> h1b (N*128 bf16, same bytes; block-local stage-then-write)
    //  R1: pre1 (N*128)  -> pre2 (pre1 dead after meanG64)
    //  R2: mean2 (N*128)
    //  R3: h0b (N*64 bf16 = N*32 f32)
    float* F = (float*)d_ws;
    float* mean1 = F;
    uint2* h1b   = (uint2*)F;
    float* pre1  = F + (size_t)N_NODES * 64;
    float* pre2  = pre1;
    float* mean2 = pre1 + (size_t)N_NODES * 128;
    uint2* h0b   = (uint2*)(mean2 + (size_t)N_NODES * 128);
    int*   deg   = (int*)((float*)h0b + (size_t)N_NODES * 32);
    float* pooled= (float*)(deg + N_NODES);           // 512*128, memset with deg
    int*   rowptr= (int*)(pooled + (size_t)N_GRAPHS * 128);  // N+1
    int*   wp    = rowptr + N_NODES + 1;              // N
    int*   nbr   = wp + N_NODES;                      // E
    int*   bsums = nbr + N_EDGES;                     // 256

    const int NB = (N_NODES + 255) / 256;             // 196
    const int GB = (N_NODES + 63) / 64;               // 782

    hipMemsetAsync(deg, 0, (size_t)N_NODES * sizeof(int)
                          + (size_t)N_GRAPHS * 128 * sizeof(float), stream);

    k_embed_hist<<<(N_EDGES + 255) / 256, 256, 0, stream>>>(x, emb, ei, h0b, deg);
    k_scanA<<<NB, 256, 0, stream>>>(deg, rowptr, bsums);
    k_scanB<<<1, 256, 0, stream>>>(bsums, NB);
    k_scanC<<<NB, 256, 0, stream>>>(rowptr, wp, bsums);
    k_scatter<<<(N_EDGES + 255) / 256, 256, 0, stream>>>(ei, wp, nbr);

    // layer 1: agg64 ∥ selfGEMM1 (2:1), then meanGEMM64 -> h1b (bf16 only)
    k_fuse1<<<3 * GB, 512, 0, stream>>>(h0b, rowptr, nbr, mean1, w1_r, b1, pre1);
    k_gemm_mean64<<<GB, 512, 0, stream>>>(mean1, w1_l, pre1, h1b);

    // layer 2: agg128 ∥ selfGEMM2 (4:1), then meanGEMM128 + fused pool
    k_fuse2<<<5 * GB, 512, 0, stream>>>(h1b, rowptr, nbr, mean2, w2_r, b2, pre2);
    k_mean128_pool<<<GB, 512, 0, stream>>>(mean2, w2_l, pre2, batch, pooled);

    // head
    k_head<<<N_GRAPHS, 128, 0, stream>>>(pooled, batch, w_out, b_out, out);

    (void)in_sizes; (void)n_in; (void)out_size; (void)ws_size;
}

// Round 11
// 331.804 us; speedup vs baseline: 1.1298x; 1.0030x over previous
//
#include <hip/hip_runtime.h>
#include <hip/hip_bf16.h>

#define N_NODES 50000
#define N_EDGES 800000
#define N_GRAPHS 512

// bf16 helpers: RNE pack, shift-unpack (bf16->f32 is exact)
__device__ __forceinline__ unsigned f2bf(float f) {
    unsigned x = __float_as_uint(f);
    return (x + 0x7fffu + ((x >> 16) & 1u)) >> 16;
}
__device__ __forceinline__ unsigned packbf(float lo, float hi) {
    return f2bf(lo) | (f2bf(hi) << 16);
}
__device__ __forceinline__ float bf_lo(unsigned u) { return __uint_as_float(u << 16); }
__device__ __forceinline__ float bf_hi(unsigned u) { return __uint_as_float(u & 0xffff0000u); }

// ------------------- embed gather (bf16 only) + degree histogram
__global__ void k_embed_hist(const int* __restrict__ x, const float* __restrict__ emb,
                             const int* __restrict__ ei, uint2* __restrict__ h0b,
                             int* __restrict__ deg) {
    int t = blockIdx.x * 256 + threadIdx.x;
    if (t >= N_EDGES) return;
    int n = t >> 4, c4 = t & 15;
    const float4* e4 = (const float4*)emb;
    float4 v = e4[(size_t)x[n] * 16 + c4];
    uint2 b; b.x = packbf(v.x, v.y); b.y = packbf(v.z, v.w);
    h0b[(size_t)n * 16 + c4] = b;
    atomicAdd(&deg[ei[N_EDGES + t]], 1);
}

// ---------------------------------------------------------------- 3-phase scan
__global__ void k_scanA(const int* __restrict__ deg, int* __restrict__ rowptr,
                        int* __restrict__ bsums) {
    __shared__ int s[256];
    int t = threadIdx.x, i = blockIdx.x * 256 + t;
    int v = (i < N_NODES) ? deg[i] : 0;
    s[t] = v; __syncthreads();
    int xv = v;
    for (int off = 1; off < 256; off <<= 1) {
        int y = (t >= off) ? s[t - off] : 0;
        __syncthreads();
        xv += y; s[t] = xv;
        __syncthreads();
    }
    if (i < N_NODES) rowptr[i] = xv - v;
    if (t == 255) bsums[blockIdx.x] = xv;
}

__global__ void k_scanB(int* __restrict__ bsums, int nb) {
    __shared__ int s[256];
    int t = threadIdx.x;
    int v = (t < nb) ? bsums[t] : 0;
    s[t] = v; __syncthreads();
    int xv = v;
    for (int off = 1; off < 256; off <<= 1) {
        int y = (t >= off) ? s[t - off] : 0;
        __syncthreads();
        xv += y; s[t] = xv;
        __syncthreads();
    }
    if (t < nb) bsums[t] = xv - v;
}

__global__ void k_scanC(int* __restrict__ rowptr, int* __restrict__ wp,
                        const int* __restrict__ bsums) {
    int i = blockIdx.x * 256 + threadIdx.x;
    if (i < N_NODES) {
        int v = rowptr[i] + bsums[blockIdx.x];
        rowptr[i] = v;
        wp[i] = v;
    }
    if (i == 0) rowptr[N_NODES] = N_EDGES;
}

// ---------------------------------------------------------------- edge scatter
__global__ void k_scatter(const int* __restrict__ ei, int* __restrict__ wp,
                          int* __restrict__ nbr) {
    int e = blockIdx.x * 256 + threadIdx.x;
    if (e >= N_EDGES) return;
    int s = ei[e], d = ei[N_EDGES + e];
    int pos = atomicAdd(&wp[d], 1);
    nbr[pos] = s;
}

// -------------------------------------------- in-LDS mean aggregation helper
// bf16 gather (proven R8 structure: whole rows, uint2/lane, 8-deep ILP),
// f32 accumulate in regs, write f32 mean row into LDS tile (stride F+2).
// F=64: 16 lanes/node, 4 nodes/wave, 32 nodes/pass. F=128: 32 lanes/node,
// 2 nodes/wave, 16 nodes/pass.
template <int F>
__device__ __forceinline__ void agg_to_lds(const uint2* __restrict__ hb,
                                           const int* __restrict__ rowptr,
                                           const int* __restrict__ nbr,
                                           int base, int pass, int t,
                                           float* __restrict__ tB) {
    constexpr int CU2 = F / 4;            // uint2 per row (= lanes per node)
    constexpr int NPW = 64 / CU2;         // nodes per wave
    constexpr int LSB = F + 2;            // LDS row stride (floats)
    int wl = t >> 6, l = t & 63;
    int nIT = pass * (8 * NPW) + wl * NPW + (l / CU2);
    int c = l & (CU2 - 1);
    int n = base + nIT;
    if (n < N_NODES) {
        int r0 = rowptr[n], r1 = rowptr[n + 1];
        float inv = 1.0f / (float)max(r1 - r0, 1);
        float4 a[8];
        #pragma unroll
        for (int u = 0; u < 8; ++u) a[u] = make_float4(0.f, 0.f, 0.f, 0.f);
        int i = r0;
        for (; i + 7 < r1; i += 8) {
            int s0 = nbr[i + 0], s1 = nbr[i + 1], s2 = nbr[i + 2], s3 = nbr[i + 3];
            int s4 = nbr[i + 4], s5 = nbr[i + 5], s6 = nbr[i + 6], s7 = nbr[i + 7];
            uint2 v0 = hb[(size_t)s0 * CU2 + c];
            uint2 v1 = hb[(size_t)s1 * CU2 + c];
            uint2 v2 = hb[(size_t)s2 * CU2 + c];
            uint2 v3 = hb[(size_t)s3 * CU2 + c];
            uint2 v4 = hb[(size_t)s4 * CU2 + c];
            uint2 v5 = hb[(size_t)s5 * CU2 + c];
            uint2 v6 = hb[(size_t)s6 * CU2 + c];
            uint2 v7 = hb[(size_t)s7 * CU2 + c];
            a[0].x += bf_lo(v0.x); a[0].y += bf_hi(v0.x); a[0].z += bf_lo(v0.y); a[0].w += bf_hi(v0.y);
            a[1].x += bf_lo(v1.x); a[1].y += bf_hi(v1.x); a[1].z += bf_lo(v1.y); a[1].w += bf_hi(v1.y);
            a[2].x += bf_lo(v2.x); a[2].y += bf_hi(v2.x); a[2].z += bf_lo(v2.y); a[2].w += bf_hi(v2.y);
            a[3].x += bf_lo(v3.x); a[3].y += bf_hi(v3.x); a[3].z += bf_lo(v3.y); a[3].w += bf_hi(v3.y);
            a[4].x += bf_lo(v4.x); a[4].y += bf_hi(v4.x); a[4].z += bf_lo(v4.y); a[4].w += bf_hi(v4.y);
            a[5].x += bf_lo(v5.x); a[5].y += bf_hi(v5.x); a[5].z += bf_lo(v5.y); a[5].w += bf_hi(v5.y);
            a[6].x += bf_lo(v6.x); a[6].y += bf_hi(v6.x); a[6].z += bf_lo(v6.y); a[6].w += bf_hi(v6.y);
            a[7].x += bf_lo(v7.x); a[7].y += bf_hi(v7.x); a[7].z += bf_lo(v7.y); a[7].w += bf_hi(v7.y);
        }
        for (; i + 3 < r1; i += 4) {
            int s0 = nbr[i + 0], s1 = nbr[i + 1], s2 = nbr[i + 2], s3 = nbr[i + 3];
            uint2 v0 = hb[(size_t)s0 * CU2 + c];
            uint2 v1 = hb[(size_t)s1 * CU2 + c];
            uint2 v2 = hb[(size_t)s2 * CU2 + c];
            uint2 v3 = hb[(size_t)s3 * CU2 + c];
            a[0].x += bf_lo(v0.x); a[0].y += bf_hi(v0.x); a[0].z += bf_lo(v0.y); a[0].w += bf_hi(v0.y);
            a[1].x += bf_lo(v1.x); a[1].y += bf_hi(v1.x); a[1].z += bf_lo(v1.y); a[1].w += bf_hi(v1.y);
            a[2].x += bf_lo(v2.x); a[2].y += bf_hi(v2.x); a[2].z += bf_lo(v2.y); a[2].w += bf_hi(v2.y);
            a[3].x += bf_lo(v3.x); a[3].y += bf_hi(v3.x); a[3].z += bf_lo(v3.y); a[3].w += bf_hi(v3.y);
        }
        for (; i < r1; ++i) {
            uint2 v = hb[(size_t)nbr[i] * CU2 + c];
            a[0].x += bf_lo(v.x); a[0].y += bf_hi(v.x); a[0].z += bf_lo(v.y); a[0].w += bf_hi(v.y);
        }
        #pragma unroll
        for (int u = 1; u < 8; ++u) {
            a[0].x += a[u].x; a[0].y += a[u].y; a[0].z += a[u].z; a[0].w += a[u].w;
        }
        float* dp = &tB[nIT * LSB + c * 4];
        dp[0] = a[0].x * inv; dp[1] = a[0].y * inv;
        dp[2] = a[0].z * inv; dp[3] = a[0].w * inv;
    }
}

// -------------------- GEMM inner cores (weights via uniform s_load streams)
template <int K>
__device__ __forceinline__ void gemm_bf_core(const unsigned* __restrict__ rowA,
                                             const float* __restrict__ w,
                                             int j0, float (&acc)[16]) {
    #pragma unroll 2
    for (int k2 = 0; k2 < K / 2; ++k2) {
        unsigned u = rowA[k2];
        float hv0 = bf_lo(u), hv1 = bf_hi(u);
        const float* w0 = &w[(size_t)(2 * k2) * 128 + j0];
        const float* w1 = &w[(size_t)(2 * k2 + 1) * 128 + j0];
        #pragma unroll
        for (int j = 0; j < 16; ++j) acc[j] = fmaf(hv0, w0[j], acc[j]);
        #pragma unroll
        for (int j = 0; j < 16; ++j) acc[j] = fmaf(hv1, w1[j], acc[j]);
    }
}

template <int K>
__device__ __forceinline__ void gemm_f32_core(const float* __restrict__ rowB,
                                              const float* __restrict__ w,
                                              int j0, float (&acc)[16]) {
    #pragma unroll 4
    for (int k = 0; k < K; ++k) {
        float hv = rowB[k];
        const float* wk = &w[(size_t)k * 128 + j0];
        #pragma unroll
        for (int j = 0; j < 16; ++j) acc[j] = fmaf(hv, wk[j], acc[j]);
    }
}

// --------------------------- layer 1: agg + selfGEMM + meanGEMM in one block
// block = 64 nodes, 512 thr. tA: h0 bf16 tile; tB: mean f32 tile.
// out: h1b bf16 only.
__global__ __launch_bounds__(512) void k_layer1(
    const uint2* __restrict__ h0b, const int* __restrict__ rowptr,
    const int* __restrict__ nbr, const float* __restrict__ w1r,
    const float* __restrict__ w1l, const float* __restrict__ b1,
    uint2* __restrict__ h1b) {
    __shared__ unsigned tA[64 * 33];          // 64 feats = 32 uints + 1 pad
    __shared__ float tB[64 * 66];
    int t = threadIdx.x, base = blockIdx.x * 64;

    for (int idx = t; idx < 1024; idx += 512) {     // 64 rows x 16 uint2
        int r = idx >> 4, c = idx & 15;
        uint2 v = (base + r < N_NODES) ? h0b[(size_t)(base + r) * 16 + c]
                                       : make_uint2(0u, 0u);
        tA[r * 33 + c * 2] = v.x; tA[r * 33 + c * 2 + 1] = v.y;
    }
    agg_to_lds<64>(h0b, rowptr, nbr, base, 0, t, tB);
    agg_to_lds<64>(h0b, rowptr, nbr, base, 1, t, tB);
    __syncthreads();

    int lane = t & 63, wid = __builtin_amdgcn_readfirstlane(t >> 6), j0 = wid * 16;
    int node = base + lane;
    float acc[16];
    #pragma unroll
    for (int j = 0; j < 16; ++j) acc[j] = b1[j0 + j];
    gemm_bf_core<64>(&tA[lane * 33], w1r, j0, acc);
    gemm_f32_core<64>(&tB[lane * 66], w1l, j0, acc);

    if (node < N_NODES) {
        #pragma unroll
        for (int jj = 0; jj < 4; ++jj) {
            float a0 = fmaxf(acc[jj * 4 + 0], 0.f), a1 = fmaxf(acc[jj * 4 + 1], 0.f);
            float a2 = fmaxf(acc[jj * 4 + 2], 0.f), a3 = fmaxf(acc[jj * 4 + 3], 0.f);
            uint2 u; u.x = packbf(a0, a1); u.y = packbf(a2, a3);
            h1b[(size_t)node * 32 + wid * 4 + jj] = u;
        }
    }
}

// ------------------- layer 2: agg + selfGEMM + meanGEMM + pool in one block
__global__ __launch_bounds__(512) void k_layer2_pool(
    const uint2* __restrict__ h1b, const int* __restrict__ rowptr,
    const int* __restrict__ nbr, const float* __restrict__ w2r,
    const float* __restrict__ w2l, const float* __restrict__ b2,
    const int* __restrict__ batch, float* __restrict__ pooled) {
    __shared__ unsigned tA[64 * 65];          // 128 feats = 64 uints + 1 pad
    __shared__ float tB[64 * 130];
    __shared__ int bb[64];
    int t = threadIdx.x, base = blockIdx.x * 64;

    for (int idx = t; idx < 2048; idx += 512) {     // 64 rows x 32 uint2
        int r = idx >> 5, c = idx & 31;
        uint2 v = (base + r < N_NODES) ? h1b[(size_t)(base + r) * 32 + c]
                                       : make_uint2(0u, 0u);
        tA[r * 65 + c * 2] = v.x; tA[r * 65 + c * 2 + 1] = v.y;
    }
    if (t < 64) bb[t] = (base + t < N_NODES) ? batch[base + t] : -1;
    #pragma unroll 1
    for (int pass = 0; pass < 4; ++pass)
        agg_to_lds<128>(h1b, rowptr, nbr, base, pass, t, tB);
    __syncthreads();

    int lane = t & 63, wid = __builtin_amdgcn_readfirstlane(t >> 6), j0 = wid * 16;
    int node = base + lane;
    bool valid = node < N_NODES;
    float acc[16];
    #pragma unroll
    for (int j = 0; j < 16; ++j) acc[j] = b2[j0 + j];
    gemm_bf_core<128>(&tA[lane * 65], w2r, j0, acc);
    gemm_f32_core<128>(&tB[lane * 130], w2l, j0, acc);
    __syncthreads();                           // tiles dead; reuse tB for pool

    #pragma unroll
    for (int j = 0; j < 16; ++j)
        tB[lane * 129 + j0 + j] = valid ? fmaxf(acc[j], 0.f) : 0.f;
    __syncthreads();

    if (t < 128) {                             // segment-reduce 64 sorted rows
        int col = t;
        float run = 0.f;
        int gcur = bb[0];
        for (int r = 0; r < 64; ++r) {
            int g = bb[r];
            if (g != gcur) {
                if (gcur >= 0) atomicAdd(&pooled[gcur * 128 + col], run);
                run = 0.f; gcur = g;
            }
            run += tB[r * 129 + col];
        }
        if (gcur >= 0) atomicAdd(&pooled[gcur * 128 + col], run);
    }
}

// ---------------------------------------------------------------- head
__global__ void k_head(const float* __restrict__ pooled, const int* __restrict__ batch,
                       const float* __restrict__ w_out, const float* __restrict__ b_out,
                       float* __restrict__ out) {
    int g = blockIdx.x, f = threadIdx.x;          // 128 threads
    int lo = 0, hi = N_NODES;
    while (lo < hi) { int m = (lo + hi) >> 1; if (batch[m] < g) lo = m + 1; else hi = m; }
    int s = lo;
    lo = s; hi = N_NODES;
    while (lo < hi) { int m = (lo + hi) >> 1; if (batch[m] < g + 1) lo = m + 1; else hi = m; }
    int cnt = lo - s;
    float p = pooled[(size_t)g * 128 + f] / (float)max(cnt, 1);
    __shared__ float red[256];
    red[f] = p * w_out[f * 2 + 0];
    red[128 + f] = p * w_out[f * 2 + 1];
    __syncthreads();
    for (int st = 64; st > 0; st >>= 1) {
        if (f < st) { red[f] += red[f + st]; red[128 + f] += red[128 + f + st]; }
        __syncthreads();
    }
    if (f == 0) {
        out[(size_t)g * 2 + 0] = red[0] + b_out[0];
        out[(size_t)g * 2 + 1] = red[128] + b_out[1];
    }
}

// ---------------------------------------------------------------- launch
extern "C" void kernel_launch(void* const* d_in, const int* in_sizes, int n_in,
                              void* d_out, int out_size, void* d_ws, size_t ws_size,
                              hipStream_t stream) {
    const int*   x      = (const int*)d_in[0];
    const int*   ei     = (const int*)d_in[1];
    const int*   batch  = (const int*)d_in[2];
    const float* emb    = (const float*)d_in[3];
    const float* w1_l   = (const float*)d_in[4];
    const float* b1     = (const float*)d_in[5];
    const float* w1_r   = (const float*)d_in[6];
    const float* w2_l   = (const float*)d_in[7];
    const float* b2     = (const float*)d_in[8];
    const float* w2_r   = (const float*)d_in[9];
    const float* w_out  = (const float*)d_in[10];
    const float* b_out  = (const float*)d_in[11];
    float* out = (float*)d_out;

    // workspace: h0b (N*64 bf16), h1b (N*128 bf16), deg, pooled, rowptr, wp, nbr
    uint2* h0b   = (uint2*)d_ws;                       // N*16 uint2
    uint2* h1b   = h0b + (size_t)N_NODES * 16;         // N*32 uint2
    int*   deg   = (int*)(h1b + (size_t)N_NODES * 32);
    float* pooled= (float*)(deg + N_NODES);            // G*128 (memset with deg)
    int*   rowptr= (int*)(pooled + (size_t)N_GRAPHS * 128);  // N+1
    int*   wp    = rowptr + N_NODES + 1;               // N
    int*   nbr   = wp + N_NODES;                       // E
    int*   bsums = nbr + N_EDGES;                      // 256

    const int NB = (N_NODES + 255) / 256;              // 196
    const int GB = (N_NODES + 63) / 64;                // 782

    hipMemsetAsync(deg, 0, (size_t)N_NODES * sizeof(int)
                          + (size_t)N_GRAPHS * 128 * sizeof(float), stream);

    k_embed_hist<<<(N_EDGES + 255) / 256, 256, 0, stream>>>(x, emb, ei, h0b, deg);
    k_scanA<<<NB, 256, 0, stream>>>(deg, rowptr, bsums);
    k_scanB<<<1, 256, 0, stream>>>(bsums, NB);
    k_scanC<<<NB, 256, 0, stream>>>(rowptr, wp, bsums);
    k_scatter<<<(N_EDGES + 255) / 256, 256, 0, stream>>>(ei, wp, nbr);

    k_layer1<<<GB, 512, 0, stream>>>(h0b, rowptr, nbr, w1_r, w1_l, b1, h1b);
    k_layer2_pool<<<GB, 512, 0, stream>>>(h1b, rowptr, nbr, w2_r, w2_l, b2,
                                          batch, pooled);
    k_head<<<N_GRAPHS, 128, 0, stream>>>(pooled, batch, w_out, b_out, out);

    (void)in_sizes; (void)n_in; (void)out_size; (void)ws_size;
}